// Round 2
// baseline (191.499 us; speedup 1.0000x reference)
//
#include <hip/hip_runtime.h>
#include <hip/hip_bf16.h>
#include <math.h>

#define VOCAB 100000
#define EMB 128
#define WIN 200
#define NT 64
#define BB 128
#define NW 128

// ---------------------------------------------------------------------------
// Kernel 0: detect mask storage (bool-1B vs int32). Reading 6400 int32 =
// 25600 B is safe under BOTH layouts (bool buffer is exactly 25600 B).
// ---------------------------------------------------------------------------
__global__ void mask_detect(const int* __restrict__ mi, int* __restrict__ flag) {
    __shared__ int s;
    if (threadIdx.x == 0) s = 0;
    __syncthreads();
    int bad = 0;
    for (int i = threadIdx.x; i < 6400; i += blockDim.x) {
        if ((unsigned)mi[i] > 1u) bad = 1;
    }
    if (bad) s = 1;
    __syncthreads();
    if (threadIdx.x == 0) flag[0] = s;
}

// ---------------------------------------------------------------------------
// Kernel 1: projection  out[row][n] = sum_e table[idx[row]][e] * Ww[n][woff+e]
// 64 rows/block, 256 threads. Thread owns n2 = tid&63 covering n={n2,n2+64},
// row-group g = tid>>6 (16 rows). 8 FMAs per staged qv b128 read (2x round 1).
// ---------------------------------------------------------------------------
__global__ __launch_bounds__(256) void proj_kernel(
    const float* __restrict__ table, const int* __restrict__ idx, int nrows,
    const float* __restrict__ Ww, int woff, const float* __restrict__ bias,
    float* __restrict__ outp)
{
    __shared__ __align__(16) float s_row[64 * 128];  // 32.7 KB
    __shared__ __align__(16) float s_W[128 * 68];    // 34.8 KB

    const int tid   = threadIdx.x;
    const int rbase = blockIdx.x * 64;
    const int n2    = tid & 63;
    const int g     = tid >> 6;
    const int r0    = g * 16;

    // stage 64 gathered rows (f4, coalesced)
    for (int i = tid; i < 2048; i += 256) {
        int r = i >> 5, e4 = i & 31;
        int ri = rbase + r;
        float4 v = make_float4(0.f, 0.f, 0.f, 0.f);
        if (ri < nrows) v = *(const float4*)&table[(size_t)idx[ri] * 128 + e4 * 4];
        ((float4*)s_row)[i] = v;
    }

    float acc0[16], acc1[16];
#pragma unroll
    for (int r = 0; r < 16; ++r) { acc0[r] = 0.f; acc1[r] = 0.f; }

    for (int c = 0; c < 2; ++c) {
        __syncthreads();
        for (int i = tid; i < 2048; i += 256) {       // W chunk [128][64] f4
            int nn = i >> 4, e4 = i & 15;
            float4 v = *(const float4*)&Ww[nn * 256 + woff + c * 64 + e4 * 4];
            *(float4*)&s_W[nn * 68 + e4 * 4] = v;
        }
        __syncthreads();
#pragma unroll
        for (int e4 = 0; e4 < 16; ++e4) {
            float4 w0v = *(const float4*)&s_W[n2 * 68 + e4 * 4];
            float4 w1v = *(const float4*)&s_W[(n2 + 64) * 68 + e4 * 4];
#pragma unroll
            for (int r = 0; r < 16; ++r) {
                float4 qv = *(const float4*)&s_row[(r0 + r) * 128 + c * 64 + e4 * 4];
                acc0[r] += w0v.x * qv.x + w0v.y * qv.y + w0v.z * qv.z + w0v.w * qv.w;
                acc1[r] += w1v.x * qv.x + w1v.y * qv.y + w1v.z * qv.z + w1v.w * qv.w;
            }
        }
    }

    const float b0 = bias ? bias[n2] : 0.f;
    const float b1 = bias ? bias[n2 + 64] : 0.f;
#pragma unroll
    for (int r = 0; r < 16; ++r) {
        int ri = rbase + r0 + r;
        if (ri < nrows) {
            outp[(size_t)ri * 128 + n2]      = acc0[r] + b0;
            outp[(size_t)ri * 128 + n2 + 64] = acc1[r] + b1;
        }
    }
}

// ---------------------------------------------------------------------------
// Kernel 2: fused att -> softmax -> PV. One block per (b, 32-t half).
// grid = 256, block = 512 (8 waves). Wave wid owns t = wid*4..wid*4+3.
// lane = w within a 64-w tile. att lives ENTIRELY in registers va[4][4]
// (4 t x 4 w-tiles); softmax = shfl reduce; PV reads att via __shfl(va, w).
// hq tile / k tile share one XOR-swizzled LDS buffer (f4-slot ^= w&7).
// ---------------------------------------------------------------------------
__global__ __launch_bounds__(512) void attn_kernel(
    const float* __restrict__ cvecs, const int* __restrict__ citems,
    const void* __restrict__ mask_raw, const int* __restrict__ flagp,
    const float* __restrict__ hwg, const float* __restrict__ hp,
    const float* __restrict__ hq, float* __restrict__ outp)
{
    __shared__ __align__(16) float s_buf[64 * 128];  // hq tile / k tile, 32.7 KB
    __shared__ __align__(16) float s_hp[32 * 128];   // [t][n], 16.4 KB
    __shared__ __align__(16) float s_hw[128];
    __shared__ float s_msk[256];
    __shared__ int   s_ci[WIN];
    __shared__ float s_inv;

    const int tid  = threadIdx.x;
    const int b    = blockIdx.x >> 1;
    const int tb   = (blockIdx.x & 1) * 32;
    const int lane = tid & 63;
    const int wid  = tid >> 6;
    const int t0   = wid * 4;

    const int boolmode = flagp[0];
    const unsigned char* mb = (const unsigned char*)mask_raw;
    const int*           mi = (const int*)mask_raw;

    // ---- initial staging: hp (32 t), hw, mask, citems row ----
    for (int i = tid; i < 1024; i += 512) {          // 32 t x 32 f4
        int t = i >> 5, e4 = i & 31;
        ((float4*)s_hp)[i] = *(const float4*)&hp[((size_t)(b * 64 + tb + t)) * 128 + e4 * 4];
    }
    if (tid < 128) s_hw[tid] = hwg[tid];
    if (tid < 256) {
        float m = 1.f;                                // w >= 200 -> masked
        if (tid < WIN) m = boolmode ? (float)mb[b * WIN + tid] : (float)mi[b * WIN + tid];
        s_msk[tid] = m;
    }
    if (tid >= 256 && tid < 256 + WIN) s_ci[tid - 256] = citems[b * WIN + (tid - 256)];
    __syncthreads();

    if (wid == 0) {                                   // 1/(1000 - masksum)^0.5
        float c = s_msk[lane] + s_msk[lane + 64] + s_msk[lane + 128]
                + ((lane < 8) ? s_msk[lane + 192] : 0.f);
        for (int off = 32; off; off >>= 1) c += __shfl_xor(c, off);
        if (lane == 0) s_inv = 1.f / sqrtf(1000.f - c);
    }

    const float* hqb = hq + (size_t)b * WIN * 128;
    const float4* buf4 = (const float4*)s_buf;
    const float4* hp4  = (const float4*)s_hp;
    const float4* hw4p = (const float4*)s_hw;

    float va[4][4];
#pragma unroll
    for (int j = 0; j < 4; ++j)
#pragma unroll
        for (int k = 0; k < 4; ++k) va[j][k] = 0.f;

    // ---- score: 4 w-tiles of 64 ----
#pragma unroll
    for (int tile = 0; tile < 4; ++tile) {
        const int w0   = tile * 64;
        const int wcnt = (tile < 3) ? 64 : (WIN - 192);
        __syncthreads();
        for (int i = tid; i < wcnt * 32; i += 512) {
            int w = i >> 5, e4 = i & 31;
            float4 v = *(const float4*)&hqb[(size_t)(w0 + w) * 128 + e4 * 4];
            ((float4*)s_buf)[w * 32 + (e4 ^ (w & 7))] = v;
        }
        __syncthreads();
        if (lane < wcnt) {
            const int base = lane * 32;
            const int lx   = lane & 7;
#pragma unroll 4
            for (int nc = 0; nc < 32; ++nc) {
                float4 hv  = buf4[base + (nc ^ lx)];
                float4 hw4 = hw4p[nc];
                float4 p0  = hp4[(t0 + 0) * 32 + nc];
                float4 p1  = hp4[(t0 + 1) * 32 + nc];
                float4 p2  = hp4[(t0 + 2) * 32 + nc];
                float4 p3  = hp4[(t0 + 3) * 32 + nc];
                va[0][tile] += hw4.x * fmaxf(hv.x + p0.x, 0.f) + hw4.y * fmaxf(hv.y + p0.y, 0.f)
                             + hw4.z * fmaxf(hv.z + p0.z, 0.f) + hw4.w * fmaxf(hv.w + p0.w, 0.f);
                va[1][tile] += hw4.x * fmaxf(hv.x + p1.x, 0.f) + hw4.y * fmaxf(hv.y + p1.y, 0.f)
                             + hw4.z * fmaxf(hv.z + p1.z, 0.f) + hw4.w * fmaxf(hv.w + p1.w, 0.f);
                va[2][tile] += hw4.x * fmaxf(hv.x + p2.x, 0.f) + hw4.y * fmaxf(hv.y + p2.y, 0.f)
                             + hw4.z * fmaxf(hv.z + p2.z, 0.f) + hw4.w * fmaxf(hv.w + p2.w, 0.f);
                va[3][tile] += hw4.x * fmaxf(hv.x + p3.x, 0.f) + hw4.y * fmaxf(hv.y + p3.y, 0.f)
                             + hw4.z * fmaxf(hv.z + p3.z, 0.f) + hw4.w * fmaxf(hv.w + p3.w, 0.f);
            }
        }
    }

    // ---- masked softmax, all in registers (wave-local) ----
    float msk[4];
#pragma unroll
    for (int k = 0; k < 4; ++k) {
        int w = lane + 64 * k;
        msk[k] = (w < WIN) ? s_msk[w] : 1.f;
    }
#pragma unroll
    for (int j = 0; j < 4; ++j) {
        float mx = -1e30f;
#pragma unroll
        for (int k = 0; k < 4; ++k) {
            float v = (msk[k] > 0.5f) ? -1e30f : va[j][k];
            va[j][k] = v;
            mx = fmaxf(mx, v);
        }
#pragma unroll
        for (int off = 32; off; off >>= 1) mx = fmaxf(mx, __shfl_xor(mx, off));
        float sum = 0.f;
#pragma unroll
        for (int k = 0; k < 4; ++k) {
            float e = (va[j][k] <= -1e29f) ? 0.f : __expf(va[j][k] - mx);
            va[j][k] = e;
            sum += e;
        }
#pragma unroll
        for (int off = 32; off; off >>= 1) sum += __shfl_xor(sum, off);
        float is = 1.f / sum;
#pragma unroll
        for (int k = 0; k < 4; ++k) va[j][k] *= is;
    }

    // ---- PV: out[t,e] = sum_w att[t,w] * k[w,e]; k tiles staged in s_buf ----
    float2 po[4];
#pragma unroll
    for (int j = 0; j < 4; ++j) po[j] = make_float2(0.f, 0.f);

    const int l2 = lane >> 1;
    const int lo = (lane & 1) * 2;
#pragma unroll
    for (int tile = 0; tile < 4; ++tile) {
        const int w0   = tile * 64;
        const int wcnt = (tile < 3) ? 64 : (WIN - 192);
        __syncthreads();
        for (int i = tid; i < wcnt * 32; i += 512) {
            int w = i >> 5, e4 = i & 31;
            float4 v = *(const float4*)&cvecs[(size_t)s_ci[w0 + w] * 128 + e4 * 4];
            ((float4*)s_buf)[w * 32 + (e4 ^ (w & 7))] = v;
        }
        __syncthreads();
        for (int w = 0; w < wcnt; ++w) {
            float a0 = __shfl(va[0][tile], w);
            float a1 = __shfl(va[1][tile], w);
            float a2 = __shfl(va[2][tile], w);
            float a3 = __shfl(va[3][tile], w);
            const float* kp = &s_buf[w * 128 + ((l2 ^ (w & 7)) << 2) + lo];
            float kx = kp[0], ky = kp[1];
            po[0].x += a0 * kx; po[0].y += a0 * ky;
            po[1].x += a1 * kx; po[1].y += a1 * ky;
            po[2].x += a2 * kx; po[2].y += a2 * ky;
            po[3].x += a3 * kx; po[3].y += a3 * ky;
        }
    }

    const float invn = s_inv;
#pragma unroll
    for (int j = 0; j < 4; ++j) {
        float2 r = make_float2(po[j].x * invn, po[j].y * invn);
        *(float2*)&outp[((size_t)(b * 64 + tb + t0 + j)) * 128 + lane * 2] = r;
    }
}

// ---------------------------------------------------------------------------
extern "C" void kernel_launch(void* const* d_in, const int* in_sizes, int n_in,
                              void* d_out, int out_size, void* d_ws, size_t ws_size,
                              hipStream_t stream) {
    const float* tvecs = (const float*)d_in[0];
    const float* cvecs = (const float*)d_in[1];
    const float* Ww    = (const float*)d_in[2];
    const float* Wb    = (const float*)d_in[3];
    const float* hw    = (const float*)d_in[4];
    // d_in[5] = h_b : unused (softmax shift-invariance)
    const int* titems  = (const int*)d_in[6];
    const int* citems  = (const int*)d_in[7];
    const void* mask   = d_in[8];
    float* out         = (float*)d_out;

    const size_t needed = (size_t)(64 + BB * NT * NW + BB * WIN * NW) * 4;
    if (ws_size < needed) return;

    int*   flag  = (int*)d_ws;
    float* hp_ws = (float*)d_ws + 64;
    float* hq_ws = hp_ws + (size_t)BB * NT * NW;

    mask_detect<<<1, 256, 0, stream>>>((const int*)mask, flag);
    proj_kernel<<<(BB * NT) / 64, 256, 0, stream>>>(tvecs, titems, BB * NT, Ww, 0, nullptr, hp_ws);
    proj_kernel<<<(BB * WIN) / 64, 256, 0, stream>>>(cvecs, citems, BB * WIN, Ww, EMB, Wb, hq_ws);
    attn_kernel<<<BB * 2, 512, 0, stream>>>(cvecs, citems, mask, flag, hw, hp_ws, hq_ws, out);
}

// Round 3
// 105.313 us; speedup vs baseline: 1.8184x; 1.8184x over previous
//
#include <hip/hip_runtime.h>
#include <hip/hip_bf16.h>
#include <math.h>

#define VOCAB 100000
#define EMB 128
#define WIN 200
#define NT 64
#define BB 128
#define NW 128

// ---------------------------------------------------------------------------
// Kernel 0: detect mask storage (bool-1B vs int32). Reading 6400 int32 =
// 25600 B is safe under BOTH layouts (bool buffer is exactly 25600 B).
// ---------------------------------------------------------------------------
__global__ void mask_detect(const int* __restrict__ mi, int* __restrict__ flag) {
    __shared__ int s;
    if (threadIdx.x == 0) s = 0;
    __syncthreads();
    int bad = 0;
    for (int i = threadIdx.x; i < 6400; i += blockDim.x) {
        if ((unsigned)mi[i] > 1u) bad = 1;
    }
    if (bad) s = 1;
    __syncthreads();
    if (threadIdx.x == 0) flag[0] = s;
}

// ---------------------------------------------------------------------------
// Kernel 0b: W^T precompute (once): WT[e][n] = Ww[n][e], e in [0,256).
// ---------------------------------------------------------------------------
__global__ void transpose_W(const float* __restrict__ Ww, float* __restrict__ WT) {
    int n = blockIdx.x;     // 128
    int e = threadIdx.x;    // 256
    WT[(size_t)e * 128 + n] = Ww[n * 256 + e];
}

// ---------------------------------------------------------------------------
// Kernel 1: projection  out[row][n] = sum_e table[idx[row]][e] * WT[eoff+e][n]
// 64 rows/block, 512 threads. Thread tile = 4 rows x 4 n (float4 acc[4], 16
// VGPR). Per 4-e step: 4 broadcast q reads + 4 contiguous W^T reads per 64
// FMAs -> VALU-bound. launch_bounds(512,4) caps VGPR at 128: no spill.
// ---------------------------------------------------------------------------
__global__ __launch_bounds__(512, 4) void proj_kernel(
    const float* __restrict__ table, const int* __restrict__ idx, int nrows,
    const float* __restrict__ WT, int eoff, const float* __restrict__ bias,
    float* __restrict__ outp)
{
    __shared__ __align__(16) float s_row[64 * 128];   // 32 KB
    __shared__ __align__(16) float s_WT[64 * 132];    // 33.8 KB (pad 128->132)

    const int tid   = threadIdx.x;
    const int rbase = blockIdx.x * 64;
    const int n0    = (tid & 31) * 4;
    const int r0    = (tid >> 5) * 4;

    // stage 64 gathered rows (f4, coalesced; idx read is broadcast per row)
    for (int i = tid; i < 64 * 32; i += 512) {
        int r = i >> 5, e4 = i & 31;
        int ri = rbase + r;
        float4 v = make_float4(0.f, 0.f, 0.f, 0.f);
        if (ri < nrows) v = *(const float4*)&table[(size_t)idx[ri] * 128 + e4 * 4];
        *(float4*)&s_row[r * 128 + e4 * 4] = v;
    }

    float4 acc[4];
#pragma unroll
    for (int i = 0; i < 4; ++i) acc[i] = make_float4(0.f, 0.f, 0.f, 0.f);

    for (int c = 0; c < 2; ++c) {
        __syncthreads();
        // stage W^T chunk [64 e][128 n] (f4 coalesced read AND write)
        for (int i = tid; i < 64 * 32; i += 512) {
            int e = i >> 5, n4 = i & 31;
            *(float4*)&s_WT[e * 132 + n4 * 4] =
                *(const float4*)&WT[(size_t)(eoff + c * 64 + e) * 128 + n4 * 4];
        }
        __syncthreads();
#pragma unroll 4
        for (int e4 = 0; e4 < 16; ++e4) {
            float4 q0 = *(const float4*)&s_row[(r0 + 0) * 128 + c * 64 + e4 * 4];
            float4 q1 = *(const float4*)&s_row[(r0 + 1) * 128 + c * 64 + e4 * 4];
            float4 q2 = *(const float4*)&s_row[(r0 + 2) * 128 + c * 64 + e4 * 4];
            float4 q3 = *(const float4*)&s_row[(r0 + 3) * 128 + c * 64 + e4 * 4];
#pragma unroll
            for (int j = 0; j < 4; ++j) {
                float4 wv = *(const float4*)&s_WT[(e4 * 4 + j) * 132 + n0];
                float a0 = ((const float*)&q0)[j];
                float a1 = ((const float*)&q1)[j];
                float a2 = ((const float*)&q2)[j];
                float a3 = ((const float*)&q3)[j];
                acc[0].x += a0 * wv.x; acc[0].y += a0 * wv.y; acc[0].z += a0 * wv.z; acc[0].w += a0 * wv.w;
                acc[1].x += a1 * wv.x; acc[1].y += a1 * wv.y; acc[1].z += a1 * wv.z; acc[1].w += a1 * wv.w;
                acc[2].x += a2 * wv.x; acc[2].y += a2 * wv.y; acc[2].z += a2 * wv.z; acc[2].w += a2 * wv.w;
                acc[3].x += a3 * wv.x; acc[3].y += a3 * wv.y; acc[3].z += a3 * wv.z; acc[3].w += a3 * wv.w;
            }
        }
    }

    float4 bv = make_float4(0.f, 0.f, 0.f, 0.f);
    if (bias) bv = *(const float4*)&bias[n0];
#pragma unroll
    for (int i = 0; i < 4; ++i) {
        int ri = rbase + r0 + i;
        if (ri < nrows) {
            float4 o;
            o.x = acc[i].x + bv.x; o.y = acc[i].y + bv.y;
            o.z = acc[i].z + bv.z; o.w = acc[i].w + bv.w;
            *(float4*)&outp[(size_t)ri * 128 + n0] = o;
        }
    }
}

// ---------------------------------------------------------------------------
// Kernel 2: fused att -> softmax -> PV. One block per (b, 16-t quarter).
// grid = 512 (2 blocks/CU), block = 256 (4 waves). Wave wid owns t0=wid*4..+3.
// lane = w within a 64-w tile. att entirely in registers va[4][4]; softmax =
// shfl; PV reads att via __shfl(va, w). hq/k tiles share XOR-swizzled s_buf.
// ---------------------------------------------------------------------------
__global__ __launch_bounds__(256, 4) void attn_kernel(
    const float* __restrict__ cvecs, const int* __restrict__ citems,
    const void* __restrict__ mask_raw, const int* __restrict__ flagp,
    const float* __restrict__ hwg, const float* __restrict__ hp,
    const float* __restrict__ hq, float* __restrict__ outp)
{
    __shared__ __align__(16) float s_buf[64 * 128];  // hq tile / k tile, 32 KB
    __shared__ __align__(16) float s_hp[16 * 128];   // [t][n], 8 KB
    __shared__ __align__(16) float s_hw[128];
    __shared__ float s_msk[256];
    __shared__ int   s_ci[WIN];
    __shared__ float s_inv;

    const int tid  = threadIdx.x;
    const int b    = blockIdx.x >> 2;
    const int tb   = (blockIdx.x & 3) * 16;
    const int lane = tid & 63;
    const int wid  = tid >> 6;
    const int t0   = wid * 4;

    const int boolmode = flagp[0];
    const unsigned char* mb = (const unsigned char*)mask_raw;
    const int*           mi = (const int*)mask_raw;

    // ---- initial staging: hp (16 t), hw, mask, citems row ----
    for (int i = tid; i < 512; i += 256) {           // 16 t x 32 f4
        int t = i >> 5, e4 = i & 31;
        ((float4*)s_hp)[i] = *(const float4*)&hp[((size_t)(b * 64 + tb + t)) * 128 + e4 * 4];
    }
    if (tid < 128) s_hw[tid] = hwg[tid];
    {
        float m = 1.f;                                // w >= 200 -> masked
        if (tid < WIN) m = boolmode ? (float)mb[b * WIN + tid] : (float)mi[b * WIN + tid];
        s_msk[tid] = m;
        if (tid < WIN) s_ci[tid] = citems[b * WIN + tid];
    }
    __syncthreads();

    if (wid == 0) {                                   // 1/(1000 - masksum)^0.5
        float c = s_msk[lane] + s_msk[lane + 64] + s_msk[lane + 128]
                + ((lane < 8) ? s_msk[lane + 192] : 0.f);
        for (int off = 32; off; off >>= 1) c += __shfl_xor(c, off);
        if (lane == 0) s_inv = 1.f / sqrtf(1000.f - c);
    }

    const float* hqb = hq + (size_t)b * WIN * 128;
    const float4* buf4 = (const float4*)s_buf;
    const float4* hp4  = (const float4*)s_hp;
    const float4* hw4p = (const float4*)s_hw;

    float va[4][4];
#pragma unroll
    for (int j = 0; j < 4; ++j)
#pragma unroll
        for (int k = 0; k < 4; ++k) va[j][k] = 0.f;

    // ---- score: 4 w-tiles of 64 ----
#pragma unroll
    for (int tile = 0; tile < 4; ++tile) {
        const int w0   = tile * 64;
        const int wcnt = (tile < 3) ? 64 : (WIN - 192);
        __syncthreads();
        for (int i = tid; i < wcnt * 32; i += 256) {
            int w = i >> 5, e4 = i & 31;
            float4 v = *(const float4*)&hqb[(size_t)(w0 + w) * 128 + e4 * 4];
            ((float4*)s_buf)[w * 32 + (e4 ^ (w & 7))] = v;
        }
        __syncthreads();
        if (lane < wcnt) {
            const int base = lane * 32;
            const int lx   = lane & 7;
#pragma unroll 4
            for (int nc = 0; nc < 32; ++nc) {
                float4 hv  = buf4[base + (nc ^ lx)];
                float4 hw4 = hw4p[nc];
                float4 p0  = hp4[(t0 + 0) * 32 + nc];
                float4 p1  = hp4[(t0 + 1) * 32 + nc];
                float4 p2  = hp4[(t0 + 2) * 32 + nc];
                float4 p3  = hp4[(t0 + 3) * 32 + nc];
                va[0][tile] += hw4.x * fmaxf(hv.x + p0.x, 0.f) + hw4.y * fmaxf(hv.y + p0.y, 0.f)
                             + hw4.z * fmaxf(hv.z + p0.z, 0.f) + hw4.w * fmaxf(hv.w + p0.w, 0.f);
                va[1][tile] += hw4.x * fmaxf(hv.x + p1.x, 0.f) + hw4.y * fmaxf(hv.y + p1.y, 0.f)
                             + hw4.z * fmaxf(hv.z + p1.z, 0.f) + hw4.w * fmaxf(hv.w + p1.w, 0.f);
                va[2][tile] += hw4.x * fmaxf(hv.x + p2.x, 0.f) + hw4.y * fmaxf(hv.y + p2.y, 0.f)
                             + hw4.z * fmaxf(hv.z + p2.z, 0.f) + hw4.w * fmaxf(hv.w + p2.w, 0.f);
                va[3][tile] += hw4.x * fmaxf(hv.x + p3.x, 0.f) + hw4.y * fmaxf(hv.y + p3.y, 0.f)
                             + hw4.z * fmaxf(hv.z + p3.z, 0.f) + hw4.w * fmaxf(hv.w + p3.w, 0.f);
            }
        }
    }

    // ---- masked softmax, all in registers (wave-local) ----
    float msk[4];
#pragma unroll
    for (int k = 0; k < 4; ++k) {
        int w = lane + 64 * k;
        msk[k] = (w < WIN) ? s_msk[w] : 1.f;
    }
#pragma unroll
    for (int j = 0; j < 4; ++j) {
        float mx = -1e30f;
#pragma unroll
        for (int k = 0; k < 4; ++k) {
            float v = (msk[k] > 0.5f) ? -1e30f : va[j][k];
            va[j][k] = v;
            mx = fmaxf(mx, v);
        }
#pragma unroll
        for (int off = 32; off; off >>= 1) mx = fmaxf(mx, __shfl_xor(mx, off));
        float sum = 0.f;
#pragma unroll
        for (int k = 0; k < 4; ++k) {
            float e = (va[j][k] <= -1e29f) ? 0.f : __expf(va[j][k] - mx);
            va[j][k] = e;
            sum += e;
        }
#pragma unroll
        for (int off = 32; off; off >>= 1) sum += __shfl_xor(sum, off);
        float is = 1.f / sum;
#pragma unroll
        for (int k = 0; k < 4; ++k) va[j][k] *= is;
    }

    // ---- PV: out[t,e] = sum_w att[t,w] * k[w,e]; k tiles staged in s_buf ----
    float2 po[4];
#pragma unroll
    for (int j = 0; j < 4; ++j) po[j] = make_float2(0.f, 0.f);

    const int l2 = lane >> 1;
    const int lo = (lane & 1) * 2;
#pragma unroll
    for (int tile = 0; tile < 4; ++tile) {
        const int w0   = tile * 64;
        const int wcnt = (tile < 3) ? 64 : (WIN - 192);
        __syncthreads();
        for (int i = tid; i < wcnt * 32; i += 256) {
            int w = i >> 5, e4 = i & 31;
            float4 v = *(const float4*)&cvecs[(size_t)s_ci[w0 + w] * 128 + e4 * 4];
            ((float4*)s_buf)[w * 32 + (e4 ^ (w & 7))] = v;
        }
        __syncthreads();
        for (int w = 0; w < wcnt; ++w) {
            float a0 = __shfl(va[0][tile], w);
            float a1 = __shfl(va[1][tile], w);
            float a2 = __shfl(va[2][tile], w);
            float a3 = __shfl(va[3][tile], w);
            const float* kp = &s_buf[w * 128 + ((l2 ^ (w & 7)) << 2) + lo];
            float kx = kp[0], ky = kp[1];
            po[0].x += a0 * kx; po[0].y += a0 * ky;
            po[1].x += a1 * kx; po[1].y += a1 * ky;
            po[2].x += a2 * kx; po[2].y += a2 * ky;
            po[3].x += a3 * kx; po[3].y += a3 * ky;
        }
    }

    const float invn = s_inv;
#pragma unroll
    for (int j = 0; j < 4; ++j) {
        float2 r = make_float2(po[j].x * invn, po[j].y * invn);
        *(float2*)&outp[((size_t)(b * 64 + tb + t0 + j)) * 128 + lane * 2] = r;
    }
}

// ---------------------------------------------------------------------------
extern "C" void kernel_launch(void* const* d_in, const int* in_sizes, int n_in,
                              void* d_out, int out_size, void* d_ws, size_t ws_size,
                              hipStream_t stream) {
    const float* tvecs = (const float*)d_in[0];
    const float* cvecs = (const float*)d_in[1];
    const float* Ww    = (const float*)d_in[2];
    const float* Wb    = (const float*)d_in[3];
    const float* hw    = (const float*)d_in[4];
    // d_in[5] = h_b : unused (softmax shift-invariance)
    const int* titems  = (const int*)d_in[6];
    const int* citems  = (const int*)d_in[7];
    const void* mask   = d_in[8];
    float* out         = (float*)d_out;

    const size_t needed = (size_t)(64 + 256 * 128 + BB * NT * NW + BB * WIN * NW) * 4;
    if (ws_size < needed) return;

    int*   flag  = (int*)d_ws;
    float* WT_ws = (float*)d_ws + 64;
    float* hp_ws = WT_ws + 256 * 128;
    float* hq_ws = hp_ws + (size_t)BB * NT * NW;

    mask_detect<<<1, 256, 0, stream>>>((const int*)mask, flag);
    transpose_W<<<128, 256, 0, stream>>>(Ww, WT_ws);
    proj_kernel<<<(BB * NT) / 64, 512, 0, stream>>>(tvecs, titems, BB * NT, WT_ws, 0, nullptr, hp_ws);
    proj_kernel<<<(BB * WIN) / 64, 512, 0, stream>>>(cvecs, citems, BB * WIN, WT_ws, EMB, Wb, hq_ws);
    attn_kernel<<<BB * 4, 256, 0, stream>>>(cvecs, citems, mask, flag, hw, hp_ws, hq_ws, out);
}

// Round 4
// 102.697 us; speedup vs baseline: 1.8647x; 1.0255x over previous
//
#include <hip/hip_runtime.h>
#include <math.h>

#define EMB 128
#define WIN 200
#define NT 64
#define BB 128
#define NW 128
#define WPAD 208   // w padded: score loads clamp into pad, softmax masks them

// ---------------------------------------------------------------------------
// Kernel 0: detect mask storage (bool-1B vs int32). Reading 6400 int32 =
// 25600 B is safe under BOTH layouts (bool buffer is exactly 25600 B).
// ---------------------------------------------------------------------------
__global__ void mask_detect(const int* __restrict__ mi, int* __restrict__ flag) {
    __shared__ int s;
    if (threadIdx.x == 0) s = 0;
    __syncthreads();
    int bad = 0;
    for (int i = threadIdx.x; i < 6400; i += blockDim.x)
        if ((unsigned)mi[i] > 1u) bad = 1;
    if (bad) s = 1;
    __syncthreads();
    if (threadIdx.x == 0) flag[0] = s;
}

// ---------------------------------------------------------------------------
// Kernel 0b: W^T precompute (once): WT[e][n] = Ww[n][e], e in [0,256).
// ---------------------------------------------------------------------------
__global__ void transpose_W(const float* __restrict__ Ww, float* __restrict__ WT) {
    int n = blockIdx.x;     // 128
    int e = threadIdx.x;    // 256
    WT[(size_t)e * 128 + n] = Ww[n * 256 + e];
}

// ---------------------------------------------------------------------------
// Kernel 1: projection  out[row][n] = sum_e table[idx[row]][e] * WT[eoff+e][n]
// tmode=0: row-major out[ri][n].
// tmode=1: transposed-interleaved hqT[b][n>>2][w][n&3] with w padded to WPAD
//          (b = ri/200, w = ri%200) — the attn score layout.
// 64 rows/block, 512 threads, 4 rows x 4 n per thread. (512,4): no spill.
// ---------------------------------------------------------------------------
__global__ __launch_bounds__(512, 4) void proj_kernel(
    const float* __restrict__ table, const int* __restrict__ idx, int nrows,
    const float* __restrict__ WT, int eoff, const float* __restrict__ bias,
    float* __restrict__ outp, int tmode)
{
    __shared__ __align__(16) float s_row[64 * 128];   // 32 KB
    __shared__ __align__(16) float s_WT[64 * 132];    // 33.8 KB (pad 128->132)

    const int tid   = threadIdx.x;
    const int rbase = blockIdx.x * 64;
    const int n0    = (tid & 31) * 4;
    const int r0    = (tid >> 5) * 4;

    for (int i = tid; i < 64 * 32; i += 512) {
        int r = i >> 5, e4 = i & 31;
        int ri = rbase + r;
        float4 v = make_float4(0.f, 0.f, 0.f, 0.f);
        if (ri < nrows) v = *(const float4*)&table[(size_t)idx[ri] * 128 + e4 * 4];
        *(float4*)&s_row[r * 128 + e4 * 4] = v;
    }

    float4 acc[4];
#pragma unroll
    for (int i = 0; i < 4; ++i) acc[i] = make_float4(0.f, 0.f, 0.f, 0.f);

    for (int c = 0; c < 2; ++c) {
        __syncthreads();
        for (int i = tid; i < 64 * 32; i += 512) {
            int e = i >> 5, n4 = i & 31;
            *(float4*)&s_WT[e * 132 + n4 * 4] =
                *(const float4*)&WT[(size_t)(eoff + c * 64 + e) * 128 + n4 * 4];
        }
        __syncthreads();
#pragma unroll 4
        for (int e4 = 0; e4 < 16; ++e4) {
            float4 q0 = *(const float4*)&s_row[(r0 + 0) * 128 + c * 64 + e4 * 4];
            float4 q1 = *(const float4*)&s_row[(r0 + 1) * 128 + c * 64 + e4 * 4];
            float4 q2 = *(const float4*)&s_row[(r0 + 2) * 128 + c * 64 + e4 * 4];
            float4 q3 = *(const float4*)&s_row[(r0 + 3) * 128 + c * 64 + e4 * 4];
#pragma unroll
            for (int j = 0; j < 4; ++j) {
                float4 wv = *(const float4*)&s_WT[(e4 * 4 + j) * 132 + n0];
                float a0 = ((const float*)&q0)[j];
                float a1 = ((const float*)&q1)[j];
                float a2 = ((const float*)&q2)[j];
                float a3 = ((const float*)&q3)[j];
                acc[0].x += a0 * wv.x; acc[0].y += a0 * wv.y; acc[0].z += a0 * wv.z; acc[0].w += a0 * wv.w;
                acc[1].x += a1 * wv.x; acc[1].y += a1 * wv.y; acc[1].z += a1 * wv.z; acc[1].w += a1 * wv.w;
                acc[2].x += a2 * wv.x; acc[2].y += a2 * wv.y; acc[2].z += a2 * wv.z; acc[2].w += a2 * wv.w;
                acc[3].x += a3 * wv.x; acc[3].y += a3 * wv.y; acc[3].z += a3 * wv.z; acc[3].w += a3 * wv.w;
            }
        }
    }

    float4 bv = make_float4(0.f, 0.f, 0.f, 0.f);
    if (bias) bv = *(const float4*)&bias[n0];
#pragma unroll
    for (int i = 0; i < 4; ++i) {
        int ri = rbase + r0 + i;
        if (ri < nrows) {
            float4 o;
            o.x = acc[i].x + bv.x; o.y = acc[i].y + bv.y;
            o.z = acc[i].z + bv.z; o.w = acc[i].w + bv.w;
            if (tmode) {
                int b2 = ri / 200;                 // magic-mul
                int wl = ri - b2 * 200;
                *(float4*)&outp[(((size_t)b2 * 32 + (n0 >> 2)) * WPAD + wl) * 4] = o;
            } else {
                *(float4*)&outp[(size_t)ri * 128 + n0] = o;
            }
        }
    }
}

// ---------------------------------------------------------------------------
// Kernel 2: fused att -> softmax -> PV. NO main-loop barriers, no big tiles.
// grid 512 = (b, 16-t quarter), block 512 = 8 waves, wave owns 2 t.
// Score: hv = one coalesced f4 (4 n) per w directly from hqT (L2-resident);
// hp/hw broadcast from tiny LDS, hoisted per n-group. att in regs va[2][4].
// Softmax: wave-local shfl. PV: per-w broadcast f2 row from cvecs + shfl att.
// XCD-chunked block swizzle keeps a b's 4 quarters on one XCD (hq L2 reuse).
// ---------------------------------------------------------------------------
__global__ __launch_bounds__(512, 4) void attn_kernel(
    const float* __restrict__ cvecs, const int* __restrict__ citems,
    const void* __restrict__ mask_raw, const int* __restrict__ flagp,
    const float* __restrict__ hwg, const float* __restrict__ hp,
    const float* __restrict__ hqT, float* __restrict__ outp)
{
    __shared__ __align__(16) float s_hp[16 * 128];   // [lt][n], 8 KB
    __shared__ __align__(16) float s_hw[128];
    __shared__ float s_msk[256];
    __shared__ int   s_ci[WIN];

    const int tid = threadIdx.x;
    const int bid = blockIdx.x;
    const int swz = (bid & 7) * 64 + (bid >> 3);     // bijective, 512 % 8 == 0
    const int b    = swz >> 2;
    const int tb   = (swz & 3) * 16;
    const int lane = tid & 63;
    const int wid  = tid >> 6;
    const int lt0  = wid * 2;

    const int boolmode = flagp[0];
    const unsigned char* mb = (const unsigned char*)mask_raw;
    const int*           mi = (const int*)mask_raw;

    // ---- stage hp (16 t, one f4 per thread), hw, mask, citems ----
    {
        int t = tid >> 5, e4 = tid & 31;
        *(float4*)&s_hp[t * 128 + e4 * 4] =
            *(const float4*)&hp[((size_t)(b * 64 + tb + t)) * 128 + e4 * 4];
    }
    if (tid < 128) s_hw[tid] = hwg[tid];
    if (tid < 256) {
        float m = 1.f;
        if (tid < WIN) m = boolmode ? (float)mb[b * WIN + tid] : (float)mi[b * WIN + tid];
        s_msk[tid] = m;
    }
    if (tid >= 256 && tid < 256 + WIN) s_ci[tid - 256] = citems[b * WIN + (tid - 256)];
    __syncthreads();   // the only block-wide barrier

    // ---- per-wave norm factor (redundant per wave; no extra barrier) ----
    float c = s_msk[lane] + s_msk[lane + 64] + s_msk[lane + 128]
            + ((lane < 8) ? s_msk[lane + 192] : 0.f);
#pragma unroll
    for (int off = 32; off; off >>= 1) c += __shfl_xor(c, off);
    const float invn = 1.f / sqrtf(1000.f - c);

    // ---- score: va[j][kt], lane = w within 64-w tile kt ----
    float va[2][4];
#pragma unroll
    for (int j = 0; j < 2; ++j)
#pragma unroll
        for (int k = 0; k < 4; ++k) va[j][k] = 0.f;

    const float4* hq4  = (const float4*)hqT + (size_t)b * 32 * WPAD;
    const float4* hp4a = (const float4*)&s_hp[lt0 * 128];
    const float4* hp4b = (const float4*)&s_hp[(lt0 + 1) * 128];
    const float4* hw4p = (const float4*)s_hw;
    const int w3 = min(192 + lane, WPAD - 1);        // clamped pad read, masked later

#define SC(J, K, HV, P)                                                        \
    va[J][K] += hwv.x * fmaxf(HV.x + P.x, 0.f) + hwv.y * fmaxf(HV.y + P.y, 0.f)\
              + hwv.z * fmaxf(HV.z + P.z, 0.f) + hwv.w * fmaxf(HV.w + P.w, 0.f);

#pragma unroll 4
    for (int nc4 = 0; nc4 < 32; ++nc4) {
        const float4* base = hq4 + (size_t)nc4 * WPAD;
        float4 hv0 = base[lane];
        float4 hv1 = base[64 + lane];
        float4 hv2 = base[128 + lane];
        float4 hv3 = base[w3];
        float4 hwv = hw4p[nc4];
        float4 p0  = hp4a[nc4];
        float4 p1  = hp4b[nc4];
        SC(0, 0, hv0, p0) SC(0, 1, hv1, p0) SC(0, 2, hv2, p0) SC(0, 3, hv3, p0)
        SC(1, 0, hv0, p1) SC(1, 1, hv1, p1) SC(1, 2, hv2, p1) SC(1, 3, hv3, p1)
    }
#undef SC

    // ---- masked softmax (wave-local, regs) ----
    float msk[4];
    msk[0] = s_msk[lane];
    msk[1] = s_msk[lane + 64];
    msk[2] = s_msk[lane + 128];
    msk[3] = s_msk[min(lane + 192, 255)];
#pragma unroll
    for (int j = 0; j < 2; ++j) {
        float mx = -1e30f;
#pragma unroll
        for (int k = 0; k < 4; ++k) {
            float v = (msk[k] > 0.5f) ? -1e30f : va[j][k];
            va[j][k] = v;
            mx = fmaxf(mx, v);
        }
#pragma unroll
        for (int off = 32; off; off >>= 1) mx = fmaxf(mx, __shfl_xor(mx, off));
        float sum = 0.f;
#pragma unroll
        for (int k = 0; k < 4; ++k) {
            float e = (va[j][k] <= -1e29f) ? 0.f : __expf(va[j][k] - mx);
            va[j][k] = e;
            sum += e;
        }
#pragma unroll
        for (int off = 32; off; off >>= 1) sum += __shfl_xor(sum, off);
        float is = 1.f / sum;
#pragma unroll
        for (int k = 0; k < 4; ++k) va[j][k] *= is;
    }

    // ---- PV: lane = e-pair; per w: broadcast f2 row + shfl att ----
    float2 po0 = make_float2(0.f, 0.f), po1 = make_float2(0.f, 0.f);
#pragma unroll
    for (int kt = 0; kt < 4; ++kt) {
        const int wcnt = (kt < 3) ? 64 : (WIN - 192);
#pragma unroll 8
        for (int w = 0; w < wcnt; ++w) {
            float a0 = __shfl(va[0][kt], w);
            float a1 = __shfl(va[1][kt], w);
            float2 kv = *(const float2*)&cvecs[(size_t)s_ci[kt * 64 + w] * 128 + lane * 2];
            po0.x += a0 * kv.x; po0.y += a0 * kv.y;
            po1.x += a1 * kv.x; po1.y += a1 * kv.y;
        }
    }

    float2 r0 = make_float2(po0.x * invn, po0.y * invn);
    float2 r1 = make_float2(po1.x * invn, po1.y * invn);
    *(float2*)&outp[((size_t)(b * 64 + tb + lt0)) * 128 + lane * 2]     = r0;
    *(float2*)&outp[((size_t)(b * 64 + tb + lt0 + 1)) * 128 + lane * 2] = r1;
}

// ---------------------------------------------------------------------------
extern "C" void kernel_launch(void* const* d_in, const int* in_sizes, int n_in,
                              void* d_out, int out_size, void* d_ws, size_t ws_size,
                              hipStream_t stream) {
    const float* tvecs = (const float*)d_in[0];
    const float* cvecs = (const float*)d_in[1];
    const float* Ww    = (const float*)d_in[2];
    const float* Wb    = (const float*)d_in[3];
    const float* hw    = (const float*)d_in[4];
    // d_in[5] = h_b : unused (softmax shift-invariance)
    const int* titems  = (const int*)d_in[6];
    const int* citems  = (const int*)d_in[7];
    const void* mask   = d_in[8];
    float* out         = (float*)d_out;

    const size_t needed = (size_t)(64 + 256 * 128 + BB * NT * NW
                                   + (size_t)BB * 32 * WPAD * 4) * 4;
    if (ws_size < needed) return;

    int*   flag   = (int*)d_ws;
    float* WT_ws  = (float*)d_ws + 64;
    float* hp_ws  = WT_ws + 256 * 128;
    float* hqT_ws = hp_ws + (size_t)BB * NT * NW;

    mask_detect<<<1, 256, 0, stream>>>((const int*)mask, flag);
    transpose_W<<<128, 256, 0, stream>>>(Ww, WT_ws);
    proj_kernel<<<(BB * NT) / 64, 512, 0, stream>>>(tvecs, titems, BB * NT, WT_ws, 0, nullptr, hp_ws, 0);
    proj_kernel<<<(BB * WIN) / 64, 512, 0, stream>>>(cvecs, citems, BB * WIN, WT_ws, EMB, Wb, hqT_ws, 1);
    attn_kernel<<<BB * 4, 512, 0, stream>>>(cvecs, citems, mask, flag, hw, hp_ws, hqT_ws, out);
}

// Round 5
// 92.809 us; speedup vs baseline: 2.0634x; 1.1065x over previous
//
#include <hip/hip_runtime.h>
#include <math.h>

#define EMB 128
#define WIN 200
#define NT 64
#define BB 128
#define NW 128
#define WPAD 208

// ---------------------------------------------------------------------------
// prep: block 0 = mask-storage detect (bool-1B vs int32; reading 6400 int32 =
// 25600 B is safe under both layouts). blocks 1..128 = W^T transpose.
// ---------------------------------------------------------------------------
__global__ void prep_kernel(const float* __restrict__ Ww, float* __restrict__ WT,
                            const int* __restrict__ mi, int* __restrict__ flag) {
    if (blockIdx.x == 0) {
        __shared__ int s;
        if (threadIdx.x == 0) s = 0;
        __syncthreads();
        int bad = 0;
        for (int i = threadIdx.x; i < 6400; i += blockDim.x)
            if ((unsigned)mi[i] > 1u) bad = 1;
        if (bad) s = 1;
        __syncthreads();
        if (threadIdx.x == 0) flag[0] = s;
    } else {
        int n = blockIdx.x - 1;   // 128
        int e = threadIdx.x;      // 256
        WT[(size_t)e * 128 + n] = Ww[n * 256 + e];
    }
}

// ---------------------------------------------------------------------------
// proj (merged hp+hq): out[row][n] = sum_e table[idx[row]][e] * WT[eoff+e][n]
// blocks [0,128) -> hp (titems, 8192 rows, row-major out);
// blocks [128,528) -> hq (citems, 25600 rows, +Wb bias, transposed-interleaved
//   hqT[b][n>>2][w][n&3], w padded to WPAD).
// 64 rows/block, 512 threads, 4 rows x 4 n per thread. (512,4): no spill.
// ---------------------------------------------------------------------------
__global__ __launch_bounds__(512, 4) void proj_kernel(
    const float* __restrict__ tvecs, const float* __restrict__ cvecs,
    const int* __restrict__ titems, const int* __restrict__ citems,
    const float* __restrict__ WT, const float* __restrict__ Wb,
    float* __restrict__ hp_out, float* __restrict__ hqT_out)
{
    __shared__ __align__(16) float s_row[64 * 128];   // 32 KB
    __shared__ __align__(16) float s_WT[64 * 132];    // 33.8 KB (pad 128->132)

    const int  tid   = threadIdx.x;
    const bool is_hp = blockIdx.x < 128;
    const float* table = is_hp ? tvecs : cvecs;
    const int*   idx   = is_hp ? titems : citems;
    const int  rbase = (is_hp ? blockIdx.x : (blockIdx.x - 128)) * 64;
    const int  eoff  = is_hp ? 0 : EMB;
    const int  n0    = (tid & 31) * 4;
    const int  r0    = (tid >> 5) * 4;

    for (int i = tid; i < 64 * 32; i += 512) {
        int r = i >> 5, e4 = i & 31;
        *(float4*)&s_row[r * 128 + e4 * 4] =
            *(const float4*)&table[(size_t)idx[rbase + r] * 128 + e4 * 4];
    }

    float4 acc[4];
#pragma unroll
    for (int i = 0; i < 4; ++i) acc[i] = make_float4(0.f, 0.f, 0.f, 0.f);

    for (int c = 0; c < 2; ++c) {
        __syncthreads();
        for (int i = tid; i < 64 * 32; i += 512) {
            int e = i >> 5, n4 = i & 31;
            *(float4*)&s_WT[e * 132 + n4 * 4] =
                *(const float4*)&WT[(size_t)(eoff + c * 64 + e) * 128 + n4 * 4];
        }
        __syncthreads();
#pragma unroll 4
        for (int e4 = 0; e4 < 16; ++e4) {
            float4 q0 = *(const float4*)&s_row[(r0 + 0) * 128 + c * 64 + e4 * 4];
            float4 q1 = *(const float4*)&s_row[(r0 + 1) * 128 + c * 64 + e4 * 4];
            float4 q2 = *(const float4*)&s_row[(r0 + 2) * 128 + c * 64 + e4 * 4];
            float4 q3 = *(const float4*)&s_row[(r0 + 3) * 128 + c * 64 + e4 * 4];
#pragma unroll
            for (int j = 0; j < 4; ++j) {
                float4 wv = *(const float4*)&s_WT[(e4 * 4 + j) * 132 + n0];
                float a0 = ((const float*)&q0)[j];
                float a1 = ((const float*)&q1)[j];
                float a2 = ((const float*)&q2)[j];
                float a3 = ((const float*)&q3)[j];
                acc[0].x += a0 * wv.x; acc[0].y += a0 * wv.y; acc[0].z += a0 * wv.z; acc[0].w += a0 * wv.w;
                acc[1].x += a1 * wv.x; acc[1].y += a1 * wv.y; acc[1].z += a1 * wv.z; acc[1].w += a1 * wv.w;
                acc[2].x += a2 * wv.x; acc[2].y += a2 * wv.y; acc[2].z += a2 * wv.z; acc[2].w += a2 * wv.w;
                acc[3].x += a3 * wv.x; acc[3].y += a3 * wv.y; acc[3].z += a3 * wv.z; acc[3].w += a3 * wv.w;
            }
        }
    }

    float4 bv = make_float4(0.f, 0.f, 0.f, 0.f);
    if (!is_hp) bv = *(const float4*)&Wb[n0];
#pragma unroll
    for (int i = 0; i < 4; ++i) {
        int ri = rbase + r0 + i;
        float4 o;
        o.x = acc[i].x + bv.x; o.y = acc[i].y + bv.y;
        o.z = acc[i].z + bv.z; o.w = acc[i].w + bv.w;
        if (is_hp) {
            *(float4*)&hp_out[(size_t)ri * 128 + n0] = o;
        } else {
            int b2 = ri / 200;                 // magic-mul
            int wl = ri - b2 * 200;
            *(float4*)&hqT_out[(((size_t)b2 * 32 + (n0 >> 2)) * WPAD + wl) * 4] = o;
        }
    }
}

// ---------------------------------------------------------------------------
// attn: fused score -> softmax -> PV with MASK COMPACTION.
// grid 1024 = (b, 8-t eighth), block 256 = 4 waves, wave owns 2 t.
// wave 0 builds the active-w list (ballot prefix-scan, m ~= 100); score
// gathers only active hq columns (f4 per n-group, L2-resident); softmax over
// m lanes in regs; PV loops m active w's with readlane att broadcast.
// ---------------------------------------------------------------------------
__device__ __forceinline__ float rdlane(float v, int l) {
    return __uint_as_float(__builtin_amdgcn_readlane(__float_as_uint(v), l));
}

__global__ __launch_bounds__(256, 4) void attn_kernel(
    const float* __restrict__ cvecs, const int* __restrict__ citems,
    const void* __restrict__ mask_raw, const int* __restrict__ flagp,
    const float* __restrict__ hwg, const float* __restrict__ hp,
    const float* __restrict__ hqT, float* __restrict__ outp)
{
    __shared__ __align__(16) float s_hp[8 * 128];    // [lt][n], 4 KB
    __shared__ __align__(16) float s_hw[128];
    __shared__ int      s_ci[WIN];
    __shared__ int      s_widx[WIN];
    __shared__ unsigned s_coff[WIN];                 // cvecs byte offsets, compacted
    __shared__ int      s_m;

    const int tid  = threadIdx.x;
    const int bid  = blockIdx.x;
    const int swz  = (bid & 7) * 128 + (bid >> 3);   // bijective, 1024 % 8 == 0
    const int b    = swz >> 3;
    const int tb   = (swz & 7) * 8;
    const int lane = tid & 63;
    const int wid  = tid >> 6;
    const int lt0  = wid * 2;

    // ---- stage hp (8 t x 32 f4: one per thread), hw, citems ----
    {
        int t = tid >> 5, e4 = tid & 31;
        *(float4*)&s_hp[t * 128 + e4 * 4] =
            *(const float4*)&hp[((size_t)(b * 64 + tb + t)) * 128 + e4 * 4];
    }
    if (tid < 128) s_hw[tid] = hwg[tid];
    if (tid < WIN) s_ci[tid] = citems[b * WIN + tid];
    __syncthreads();

    // ---- wave 0: ballot prefix-scan -> compacted active-w list ----
    if (wid == 0) {
        const int boolmode = flagp[0];
        const unsigned char* mb = (const unsigned char*)mask_raw;
        const int*           mi = (const int*)mask_raw;
        int base = 0;
#pragma unroll
        for (int r = 0; r < 4; ++r) {
            int w  = r * 64 + lane;
            int mv = 1;
            if (w < WIN) mv = boolmode ? (int)mb[b * WIN + w] : mi[b * WIN + w];
            unsigned long long act = __ballot(mv == 0);
            if (mv == 0)
                s_widx[base + __popcll(act & ((1ull << lane) - 1ull))] = w;
            base += __popcll(act);
        }
        if (lane == 0) s_m = base;
    }
    __syncthreads();

    const int m = s_m;
    if (m == 0) {                                    // degenerate (never with random mask)
        size_t orow = ((size_t)(b * 64 + tb + lt0)) * 128;
        *(float2*)&outp[orow + lane * 2]       = make_float2(0.f, 0.f);
        *(float2*)&outp[orow + 128 + lane * 2] = make_float2(0.f, 0.f);
        return;
    }
    if (tid < m) s_coff[tid] = (unsigned)s_ci[s_widx[tid]] * 512u;
    const float invn = 1.f / sqrtf(800.f + (float)m);   // 1000 - (200 - m)

    int wreg[4];
    const int mc = m - 1;
#pragma unroll
    for (int kt = 0; kt < 4; ++kt)
        wreg[kt] = s_widx[min(kt * 64 + lane, mc)];  // clamped; junk masked later
    __syncthreads();                                  // s_coff visible for PV

    // ---- score over compacted w's ----
    const float4* hq4  = (const float4*)hqT + (size_t)b * 32 * WPAD;
    const float4* hp4a = (const float4*)&s_hp[lt0 * 128];
    const float4* hp4b = hp4a + 32;
    const float4* hw4p = (const float4*)s_hw;

    float va[2][4];
#pragma unroll
    for (int j = 0; j < 2; ++j)
#pragma unroll
        for (int k = 0; k < 4; ++k) va[j][k] = 0.f;

#define SC(J, K, HV, P)                                                        \
    va[J][K] += hwv.x * fmaxf(HV.x + P.x, 0.f) + hwv.y * fmaxf(HV.y + P.y, 0.f)\
              + hwv.z * fmaxf(HV.z + P.z, 0.f) + hwv.w * fmaxf(HV.w + P.w, 0.f);

    if (m <= 128) {                                   // fast path (~always)
#pragma unroll 4
        for (int nc = 0; nc < 32; ++nc) {
            const float4* base = hq4 + (size_t)nc * WPAD;
            float4 hv0 = base[wreg[0]];
            float4 hv1 = base[wreg[1]];
            float4 hwv = hw4p[nc];
            float4 p0  = hp4a[nc];
            float4 p1  = hp4b[nc];
            SC(0, 0, hv0, p0) SC(0, 1, hv1, p0)
            SC(1, 0, hv0, p1) SC(1, 1, hv1, p1)
        }
    } else {
#pragma unroll 2
        for (int nc = 0; nc < 32; ++nc) {
            const float4* base = hq4 + (size_t)nc * WPAD;
            float4 hv0 = base[wreg[0]];
            float4 hv1 = base[wreg[1]];
            float4 hv2 = base[wreg[2]];
            float4 hv3 = base[wreg[3]];
            float4 hwv = hw4p[nc];
            float4 p0  = hp4a[nc];
            float4 p1  = hp4b[nc];
            SC(0, 0, hv0, p0) SC(0, 1, hv1, p0) SC(0, 2, hv2, p0) SC(0, 3, hv3, p0)
            SC(1, 0, hv0, p1) SC(1, 1, hv1, p1) SC(1, 2, hv2, p1) SC(1, 3, hv3, p1)
        }
    }
#undef SC

    // ---- softmax over m compacted lanes (regs, wave-local) ----
#pragma unroll
    for (int j = 0; j < 2; ++j) {
        float mx = -1e30f;
#pragma unroll
        for (int kt = 0; kt < 4; ++kt) {
            float v = (kt * 64 + lane < m) ? va[j][kt] : -1e30f;
            va[j][kt] = v;
            mx = fmaxf(mx, v);
        }
#pragma unroll
        for (int off = 32; off; off >>= 1) mx = fmaxf(mx, __shfl_xor(mx, off));
        float sum = 0.f;
#pragma unroll
        for (int kt = 0; kt < 4; ++kt) {
            float e = (va[j][kt] <= -1e29f) ? 0.f : __expf(va[j][kt] - mx);
            va[j][kt] = e;
            sum += e;
        }
#pragma unroll
        for (int off = 32; off; off >>= 1) sum += __shfl_xor(sum, off);
        float is = 1.f / sum;
#pragma unroll
        for (int kt = 0; kt < 4; ++kt) va[j][kt] *= is;
    }

    // ---- PV over m active w's: lane = e-pair, att via readlane ----
    float2 po0 = make_float2(0.f, 0.f), po1 = make_float2(0.f, 0.f);
    const char* cvb = (const char*)cvecs;
#pragma unroll
    for (int kt = 0; kt < 4; ++kt) {
        if (kt * 64 < m) {
            const int wn = min(64, m - kt * 64);
#pragma unroll 4
            for (int w = 0; w < wn; ++w) {
                unsigned off = s_coff[kt * 64 + w];
                float2 kv = *(const float2*)(cvb + off + lane * 8);
                float a0 = rdlane(va[0][kt], w);
                float a1 = rdlane(va[1][kt], w);
                po0.x += a0 * kv.x; po0.y += a0 * kv.y;
                po1.x += a1 * kv.x; po1.y += a1 * kv.y;
            }
        }
    }

    size_t orow = ((size_t)(b * 64 + tb + lt0)) * 128;
    *(float2*)&outp[orow + lane * 2]       = make_float2(po0.x * invn, po0.y * invn);
    *(float2*)&outp[orow + 128 + lane * 2] = make_float2(po1.x * invn, po1.y * invn);
}

// ---------------------------------------------------------------------------
extern "C" void kernel_launch(void* const* d_in, const int* in_sizes, int n_in,
                              void* d_out, int out_size, void* d_ws, size_t ws_size,
                              hipStream_t stream) {
    const float* tvecs = (const float*)d_in[0];
    const float* cvecs = (const float*)d_in[1];
    const float* Ww    = (const float*)d_in[2];
    const float* Wb    = (const float*)d_in[3];
    const float* hw    = (const float*)d_in[4];
    // d_in[5] = h_b : unused (softmax shift-invariance)
    const int* titems  = (const int*)d_in[6];
    const int* citems  = (const int*)d_in[7];
    const void* mask   = d_in[8];
    float* out         = (float*)d_out;

    const size_t needed = (size_t)(64 + 256 * 128 + BB * NT * NW
                                   + (size_t)BB * 32 * WPAD * 4) * 4;
    if (ws_size < needed) return;

    int*   flag   = (int*)d_ws;
    float* WT_ws  = (float*)d_ws + 64;
    float* hp_ws  = WT_ws + 256 * 128;
    float* hqT_ws = hp_ws + (size_t)BB * NT * NW;

    prep_kernel<<<129, 256, 0, stream>>>(Ww, WT_ws, (const int*)mask, flag);
    proj_kernel<<<528, 512, 0, stream>>>(tvecs, cvecs, titems, citems,
                                         WT_ws, Wb, hp_ws, hqT_ws);
    attn_kernel<<<BB * 8, 256, 0, stream>>>(cvecs, citems, mask, flag,
                                            hw, hp_ws, hqT_ws, out);
}

// Round 6
// 75.703 us; speedup vs baseline: 2.5296x; 1.2260x over previous
//
#include <hip/hip_runtime.h>
#include <math.h>

#define EMB 128
#define WIN 200
#define NT 64
#define BB 128
#define NW 128
#define WPAD 208

// ---------------------------------------------------------------------------
// prep: block 0 = mask-storage detect (bool-1B vs int32; reading 6400 int32 =
// 25600 B is safe under both layouts). blocks 1..128 = W^T transpose.
// ---------------------------------------------------------------------------
__global__ void prep_kernel(const float* __restrict__ Ww, float* __restrict__ WT,
                            const int* __restrict__ mi, int* __restrict__ flag) {
    if (blockIdx.x == 0) {
        __shared__ int s;
        if (threadIdx.x == 0) s = 0;
        __syncthreads();
        int bad = 0;
        for (int i = threadIdx.x; i < 6400; i += blockDim.x)
            if ((unsigned)mi[i] > 1u) bad = 1;
        if (bad) s = 1;
        __syncthreads();
        if (threadIdx.x == 0) flag[0] = s;
    } else {
        int n = blockIdx.x - 1;   // 128
        int e = threadIdx.x;      // 256
        WT[(size_t)e * 128 + n] = Ww[n * 256 + e];
    }
}

// ---------------------------------------------------------------------------
// proj (merged hp+hq): out[row][n] = sum_e table[idx[row]][e] * WT[eoff+e][n]
// blocks [0,128) -> hp (titems, row-major); [128,528) -> hq (citems, +Wb,
// transposed-interleaved hqT[b][n>>2][w][n&3], w padded to WPAD).
// ---------------------------------------------------------------------------
__global__ __launch_bounds__(512, 4) void proj_kernel(
    const float* __restrict__ tvecs, const float* __restrict__ cvecs,
    const int* __restrict__ titems, const int* __restrict__ citems,
    const float* __restrict__ WT, const float* __restrict__ Wb,
    float* __restrict__ hp_out, float* __restrict__ hqT_out)
{
    __shared__ __align__(16) float s_row[64 * 128];   // 32 KB
    __shared__ __align__(16) float s_WT[64 * 132];    // 33.8 KB

    const int  tid   = threadIdx.x;
    const bool is_hp = blockIdx.x < 128;
    const float* table = is_hp ? tvecs : cvecs;
    const int*   idx   = is_hp ? titems : citems;
    const int  rbase = (is_hp ? blockIdx.x : (blockIdx.x - 128)) * 64;
    const int  eoff  = is_hp ? 0 : EMB;
    const int  n0    = (tid & 31) * 4;
    const int  r0    = (tid >> 5) * 4;

    for (int i = tid; i < 64 * 32; i += 512) {
        int r = i >> 5, e4 = i & 31;
        *(float4*)&s_row[r * 128 + e4 * 4] =
            *(const float4*)&table[(size_t)idx[rbase + r] * 128 + e4 * 4];
    }

    float4 acc[4];
#pragma unroll
    for (int i = 0; i < 4; ++i) acc[i] = make_float4(0.f, 0.f, 0.f, 0.f);

    for (int c = 0; c < 2; ++c) {
        __syncthreads();
        for (int i = tid; i < 64 * 32; i += 512) {
            int e = i >> 5, n4 = i & 31;
            *(float4*)&s_WT[e * 132 + n4 * 4] =
                *(const float4*)&WT[(size_t)(eoff + c * 64 + e) * 128 + n4 * 4];
        }
        __syncthreads();
#pragma unroll 4
        for (int e4 = 0; e4 < 16; ++e4) {
            float4 q0 = *(const float4*)&s_row[(r0 + 0) * 128 + c * 64 + e4 * 4];
            float4 q1 = *(const float4*)&s_row[(r0 + 1) * 128 + c * 64 + e4 * 4];
            float4 q2 = *(const float4*)&s_row[(r0 + 2) * 128 + c * 64 + e4 * 4];
            float4 q3 = *(const float4*)&s_row[(r0 + 3) * 128 + c * 64 + e4 * 4];
#pragma unroll
            for (int j = 0; j < 4; ++j) {
                float4 wv = *(const float4*)&s_WT[(e4 * 4 + j) * 132 + n0];
                float a0 = ((const float*)&q0)[j];
                float a1 = ((const float*)&q1)[j];
                float a2 = ((const float*)&q2)[j];
                float a3 = ((const float*)&q3)[j];
                acc[0].x += a0 * wv.x; acc[0].y += a0 * wv.y; acc[0].z += a0 * wv.z; acc[0].w += a0 * wv.w;
                acc[1].x += a1 * wv.x; acc[1].y += a1 * wv.y; acc[1].z += a1 * wv.z; acc[1].w += a1 * wv.w;
                acc[2].x += a2 * wv.x; acc[2].y += a2 * wv.y; acc[2].z += a2 * wv.z; acc[2].w += a2 * wv.w;
                acc[3].x += a3 * wv.x; acc[3].y += a3 * wv.y; acc[3].z += a3 * wv.z; acc[3].w += a3 * wv.w;
            }
        }
    }

    float4 bv = make_float4(0.f, 0.f, 0.f, 0.f);
    if (!is_hp) bv = *(const float4*)&Wb[n0];
#pragma unroll
    for (int i = 0; i < 4; ++i) {
        int ri = rbase + r0 + i;
        float4 o;
        o.x = acc[i].x + bv.x; o.y = acc[i].y + bv.y;
        o.z = acc[i].z + bv.z; o.w = acc[i].w + bv.w;
        if (is_hp) {
            *(float4*)&hp_out[(size_t)ri * 128 + n0] = o;
        } else {
            int b2 = ri / 200;
            int wl = ri - b2 * 200;
            *(float4*)&hqT_out[(((size_t)b2 * 32 + (n0 >> 2)) * WPAD + wl) * 4] = o;
        }
    }
}

// ---------------------------------------------------------------------------
// attn: one block per (b, 32-t half). 512 thr = 8 waves x 4 t.
// Compacted hq (64KB) + compacted k rows (64KB) staged ONCE per block in LDS;
// score/softmax/PV run from LDS/regs. m>128 fallback: direct-from-L2 path.
// ---------------------------------------------------------------------------
__device__ __forceinline__ float rdlane(float v, int l) {
    return __uint_as_float(__builtin_amdgcn_readlane(__float_as_uint(v), l));
}

__global__ __launch_bounds__(512, 2) void attn_kernel(
    const float* __restrict__ cvecs, const int* __restrict__ citems,
    const void* __restrict__ mask_raw, const int* __restrict__ flagp,
    const float* __restrict__ hwg, const float* __restrict__ hp,
    const float* __restrict__ hqT, float* __restrict__ outp)
{
    __shared__ __align__(16) float4 s_hq4[32 * 128];  // [nc][w'] 64 KB
    __shared__ __align__(16) float4 s_k4[128 * 32];   // [w'][e4] 64 KB
    __shared__ __align__(16) float  s_hp[32 * 128];   // [lt][n] 16 KB
    __shared__ __align__(16) float  s_hw[128];
    __shared__ int s_ci[WIN];
    __shared__ int s_widx[WIN];
    __shared__ int s_m;

    const int tid  = threadIdx.x;
    const int b    = blockIdx.x >> 1;
    const int tb   = (blockIdx.x & 1) * 32;
    const int lane = tid & 63;
    const int wid  = tid >> 6;
    const int t0   = wid * 4;

    // ---- stage hp (32 t), hw, citems; wave 0 also builds compaction ----
    for (int i = tid; i < 1024; i += 512) {
        int t = i >> 5, e4 = i & 31;
        *(float4*)&s_hp[t * 128 + e4 * 4] =
            *(const float4*)&hp[((size_t)(b * 64 + tb + t)) * 128 + e4 * 4];
    }
    if (tid < 128) s_hw[tid] = hwg[tid];
    if (tid < WIN) s_ci[tid] = citems[b * WIN + tid];
    if (wid == 0) {
        const int boolmode = flagp[0];
        const unsigned char* mb = (const unsigned char*)mask_raw;
        const int*           mi = (const int*)mask_raw;
        int base = 0;
#pragma unroll
        for (int r = 0; r < 4; ++r) {
            int w  = r * 64 + lane;
            int mv = 1;
            if (w < WIN) mv = boolmode ? (int)mb[b * WIN + w] : mi[b * WIN + w];
            unsigned long long act = __ballot(mv == 0);
            if (mv == 0)
                s_widx[base + __popcll(act & ((1ull << lane) - 1ull))] = w;
            base += __popcll(act);
        }
        if (lane == 0) s_m = base;
    }
    __syncthreads();

    const int m = s_m;
    const float invn = 1.f / sqrtf(800.f + (float)m);   // 1000 - (200 - m)
    size_t orow = ((size_t)(b * 64 + tb + t0)) * 128;

    if (m == 0) {
#pragma unroll
        for (int j = 0; j < 4; ++j)
            *(float2*)&outp[orow + (size_t)j * 128 + lane * 2] = make_float2(0.f, 0.f);
        return;
    }

    const float4* hq4  = (const float4*)hqT + (size_t)b * 32 * WPAD;
    const float4* hp4a = (const float4*)&s_hp[t0 * 128];
    const float4* hw4p = (const float4*)s_hw;
    const float4* cv4  = (const float4*)cvecs;

#define SC(J, K, HV, P)                                                        \
    va[J][K] += hwv.x * fmaxf(HV.x + P.x, 0.f) + hwv.y * fmaxf(HV.y + P.y, 0.f)\
              + hwv.z * fmaxf(HV.z + P.z, 0.f) + hwv.w * fmaxf(HV.w + P.w, 0.f);

    if (m <= 128) {
        // ======================= staged fast path =======================
        {   // hq: [nc][w'] gather once
            const int w2 = tid & 127, nc0 = tid >> 7;
            if (w2 < m) {
                const int wi = s_widx[w2];
#pragma unroll
                for (int nc = nc0; nc < 32; nc += 4)
                    s_hq4[nc * 128 + w2] = hq4[(size_t)nc * WPAD + wi];
            }
            // k: [w'][e4] gather once (rows coalesced by 32 threads)
            const int e4 = tid & 31, w0 = tid >> 5;
            for (int w2k = w0; w2k < m; w2k += 16) {
                int ci = s_ci[s_widx[w2k]];
                s_k4[w2k * 32 + e4] = cv4[(size_t)ci * 32 + e4];
            }
        }
        __syncthreads();

        float va[4][2];
#pragma unroll
        for (int j = 0; j < 4; ++j) { va[j][0] = 0.f; va[j][1] = 0.f; }

#pragma unroll 2
        for (int nc = 0; nc < 32; ++nc) {
            float4 hv0 = s_hq4[nc * 128 + lane];
            float4 hv1 = s_hq4[nc * 128 + 64 + lane];
            float4 hwv = hw4p[nc];
            float4 p0  = hp4a[0 * 32 + nc];
            float4 p1  = hp4a[1 * 32 + nc];
            float4 p2  = hp4a[2 * 32 + nc];
            float4 p3  = hp4a[3 * 32 + nc];
            SC(0, 0, hv0, p0) SC(0, 1, hv1, p0)
            SC(1, 0, hv0, p1) SC(1, 1, hv1, p1)
            SC(2, 0, hv0, p2) SC(2, 1, hv1, p2)
            SC(3, 0, hv0, p3) SC(3, 1, hv1, p3)
        }

        // softmax over m compacted lanes (2 tiles)
#pragma unroll
        for (int j = 0; j < 4; ++j) {
            float mx = -1e30f;
#pragma unroll
            for (int kt = 0; kt < 2; ++kt) {
                float v = (kt * 64 + lane < m) ? va[j][kt] : -1e30f;
                va[j][kt] = v;
                mx = fmaxf(mx, v);
            }
#pragma unroll
            for (int off = 32; off; off >>= 1) mx = fmaxf(mx, __shfl_xor(mx, off));
            float sum = 0.f;
#pragma unroll
            for (int kt = 0; kt < 2; ++kt) {
                float e = (va[j][kt] <= -1e29f) ? 0.f : __expf(va[j][kt] - mx);
                va[j][kt] = e;
                sum += e;
            }
#pragma unroll
            for (int off = 32; off; off >>= 1) sum += __shfl_xor(sum, off);
            float is = 1.f / sum;
            va[j][0] *= is; va[j][1] *= is;
        }

        // PV from LDS k rows, att via readlane
        float2 po[4];
#pragma unroll
        for (int j = 0; j < 4; ++j) po[j] = make_float2(0.f, 0.f);
        const float2* s_k2 = (const float2*)s_k4;
#pragma unroll
        for (int kt = 0; kt < 2; ++kt) {
            if (kt * 64 < m) {
                const int wn = min(64, m - kt * 64);
                for (int w = 0; w < wn; ++w) {
                    float2 kv = s_k2[(kt * 64 + w) * 64 + lane];
                    float a0 = rdlane(va[0][kt], w);
                    float a1 = rdlane(va[1][kt], w);
                    float a2 = rdlane(va[2][kt], w);
                    float a3 = rdlane(va[3][kt], w);
                    po[0].x += a0 * kv.x; po[0].y += a0 * kv.y;
                    po[1].x += a1 * kv.x; po[1].y += a1 * kv.y;
                    po[2].x += a2 * kv.x; po[2].y += a2 * kv.y;
                    po[3].x += a3 * kv.x; po[3].y += a3 * kv.y;
                }
            }
        }
#pragma unroll
        for (int j = 0; j < 4; ++j)
            *(float2*)&outp[orow + (size_t)j * 128 + lane * 2] =
                make_float2(po[j].x * invn, po[j].y * invn);
    } else {
        // ================== direct fallback (m > 128, rare) ==================
        int wreg[4];
        const int mc = m - 1;
#pragma unroll
        for (int kt = 0; kt < 4; ++kt)
            wreg[kt] = s_widx[min(kt * 64 + lane, mc)];

        float va[4][4];
#pragma unroll
        for (int j = 0; j < 4; ++j)
#pragma unroll
            for (int k = 0; k < 4; ++k) va[j][k] = 0.f;

#pragma unroll 2
        for (int nc = 0; nc < 32; ++nc) {
            const float4* base = hq4 + (size_t)nc * WPAD;
            float4 hv0 = base[wreg[0]];
            float4 hv1 = base[wreg[1]];
            float4 hv2 = base[wreg[2]];
            float4 hv3 = base[wreg[3]];
            float4 hwv = hw4p[nc];
            float4 p0  = hp4a[0 * 32 + nc];
            float4 p1  = hp4a[1 * 32 + nc];
            float4 p2  = hp4a[2 * 32 + nc];
            float4 p3  = hp4a[3 * 32 + nc];
            SC(0, 0, hv0, p0) SC(0, 1, hv1, p0) SC(0, 2, hv2, p0) SC(0, 3, hv3, p0)
            SC(1, 0, hv0, p1) SC(1, 1, hv1, p1) SC(1, 2, hv2, p1) SC(1, 3, hv3, p1)
            SC(2, 0, hv0, p2) SC(2, 1, hv1, p2) SC(2, 2, hv2, p2) SC(2, 3, hv3, p2)
            SC(3, 0, hv0, p3) SC(3, 1, hv1, p3) SC(3, 2, hv2, p3) SC(3, 3, hv3, p3)
        }

#pragma unroll
        for (int j = 0; j < 4; ++j) {
            float mx = -1e30f;
#pragma unroll
            for (int kt = 0; kt < 4; ++kt) {
                float v = (kt * 64 + lane < m) ? va[j][kt] : -1e30f;
                va[j][kt] = v;
                mx = fmaxf(mx, v);
            }
#pragma unroll
            for (int off = 32; off; off >>= 1) mx = fmaxf(mx, __shfl_xor(mx, off));
            float sum = 0.f;
#pragma unroll
            for (int kt = 0; kt < 4; ++kt) {
                float e = (va[j][kt] <= -1e29f) ? 0.f : __expf(va[j][kt] - mx);
                va[j][kt] = e;
                sum += e;
            }
#pragma unroll
            for (int off = 32; off; off >>= 1) sum += __shfl_xor(sum, off);
            float is = 1.f / sum;
#pragma unroll
            for (int kt = 0; kt < 4; ++kt) va[j][kt] *= is;
        }

        float2 po[4];
#pragma unroll
        for (int j = 0; j < 4; ++j) po[j] = make_float2(0.f, 0.f);
        const char* cvb = (const char*)cvecs;
#pragma unroll
        for (int kt = 0; kt < 4; ++kt) {
            if (kt * 64 < m) {
                const int wn = min(64, m - kt * 64);
                for (int w = 0; w < wn; ++w) {
                    unsigned off = (unsigned)s_ci[s_widx[kt * 64 + w]] * 512u;
                    float2 kv = *(const float2*)(cvb + off + lane * 8);
                    float a0 = rdlane(va[0][kt], w);
                    float a1 = rdlane(va[1][kt], w);
                    float a2 = rdlane(va[2][kt], w);
                    float a3 = rdlane(va[3][kt], w);
                    po[0].x += a0 * kv.x; po[0].y += a0 * kv.y;
                    po[1].x += a1 * kv.x; po[1].y += a1 * kv.y;
                    po[2].x += a2 * kv.x; po[2].y += a2 * kv.y;
                    po[3].x += a3 * kv.x; po[3].y += a3 * kv.y;
                }
            }
        }
#pragma unroll
        for (int j = 0; j < 4; ++j)
            *(float2*)&outp[orow + (size_t)j * 128 + lane * 2] =
                make_float2(po[j].x * invn, po[j].y * invn);
    }
#undef SC
}

// ---------------------------------------------------------------------------
extern "C" void kernel_launch(void* const* d_in, const int* in_sizes, int n_in,
                              void* d_out, int out_size, void* d_ws, size_t ws_size,
                              hipStream_t stream) {
    const float* tvecs = (const float*)d_in[0];
    const float* cvecs = (const float*)d_in[1];
    const float* Ww    = (const float*)d_in[2];
    const float* Wb    = (const float*)d_in[3];
    const float* hw    = (const float*)d_in[4];
    // d_in[5] = h_b : unused (softmax shift-invariance)
    const int* titems  = (const int*)d_in[6];
    const int* citems  = (const int*)d_in[7];
    const void* mask   = d_in[8];
    float* out         = (float*)d_out;

    const size_t needed = (size_t)(64 + 256 * 128 + BB * NT * NW
                                   + (size_t)BB * 32 * WPAD * 4) * 4;
    if (ws_size < needed) return;

    int*   flag   = (int*)d_ws;
    float* WT_ws  = (float*)d_ws + 64;
    float* hp_ws  = WT_ws + 256 * 128;
    float* hqT_ws = hp_ws + (size_t)BB * NT * NW;

    prep_kernel<<<129, 256, 0, stream>>>(Ww, WT_ws, (const int*)mask, flag);
    proj_kernel<<<528, 512, 0, stream>>>(tvecs, cvecs, titems, citems,
                                         WT_ws, Wb, hp_ws, hqT_ws);
    attn_kernel<<<BB * 2, 512, 0, stream>>>(cvecs, citems, mask, flag,
                                            hw, hp_ws, hqT_ws, out);
}